// Round 17
// baseline (508.220 us; speedup 1.0000x reference)
//
#include <hip/hip_runtime.h>
#include <hip/hip_fp16.h>

#define NN 100000
#define NE 3200000
#define NG 2000
#define FIN 14
#define HD 64
#define NC 2

#define NBUK 256
#define BNODES 391      // 256*391 = 100096 >= NN
#define P1E 4096        // edges per pass-1 block
#define BUFCAP 13312    // pass-2 LDS csr slice capacity (mean 12500, +7 sigma)

typedef unsigned int uint;
typedef short short8 __attribute__((ext_vector_type(8)));
typedef float f32x4 __attribute__((ext_vector_type(4)));
union U128 { uint4 u; short8 s; };

__device__ __forceinline__ __half2 u2h(uint u) {
    union { uint u; __half2 h; } c; c.u = u; return c.h;
}
__device__ __forceinline__ uint h2u(__half2 h) {
    union { __half2 h; uint u; } c; c.h = h; return c.u;
}
__device__ __forceinline__ uint pkh(float a, float b) {
    return h2u(__floats2half2_rn(a, b));
}
__device__ __forceinline__ uint pack2bf16(float a, float b) {
    uint ua = __float_as_uint(a), ub = __float_as_uint(b);
    ua = (ua + 0x7FFFu + ((ua >> 16) & 1u)) >> 16;
    ub = (ub + 0x7FFFu + ((ub >> 16) & 1u)) >> 16;
    return ua | (ub << 16);
}
__device__ __forceinline__ short bf16of(float a) {
    uint ua = __float_as_uint(a);
    return (short)((ua + 0x7FFFu + ((ua >> 16) & 1u)) >> 16);
}
// packed-fp16 xor-reduce step
__device__ __forceinline__ __half2 hredx(__half2 v, int off) {
    return __hadd2(v, u2h((uint)__shfl_xor((int)h2u(v), off)));
}

// ---------------- bucket histogram (LDS-privatized) ----------------

__global__ __launch_bounds__(256) void k_hist_bucket(const int* __restrict__ dst,
                                                     int* __restrict__ bkcnt) {
    __shared__ int cnt[NBUK];
    int t = threadIdx.x;
    cnt[t] = 0;
    __syncthreads();
    int e0 = blockIdx.x * P1E;
    int m = NE - e0; if (m > P1E) m = P1E;
    for (int e = t; e < m; e += 256) atomicAdd(&cnt[dst[e0 + e] / BNODES], 1);
    __syncthreads();
    if (cnt[t] > 0) atomicAdd(&bkcnt[t], cnt[t]);
}

__global__ void k_scanb(const int* __restrict__ bkcnt, int* __restrict__ bbase,
                        int* __restrict__ bcur) {
    __shared__ int tmp[NBUK];
    int t = threadIdx.x;
    int v = bkcnt[t];
    tmp[t] = v;
    __syncthreads();
    for (int off = 1; off < NBUK; off <<= 1) {
        int u = (t >= off) ? tmp[t - off] : 0;
        __syncthreads();
        tmp[t] += u;
        __syncthreads();
    }
    int excl = tmp[t] - v;
    bbase[t] = excl;
    bcur[t] = excl;
    if (t == NBUK - 1) bbase[NBUK] = tmp[t];
}

__global__ void k_gbounds(const int* __restrict__ batch, int* __restrict__ gstart,
                          int* __restrict__ gend) {
    int i = blockIdx.x * blockDim.x + threadIdx.x;
    if (i < NN) {
        int b = batch[i];
        if (i == 0 || batch[i - 1] != b) gstart[b] = i;
        if (i == NN - 1 || batch[i + 1] != b) gend[b] = i + 1;
    }
}

__global__ __launch_bounds__(256) void k_pass1(
    const int* __restrict__ src, const int* __restrict__ dst,
    int* __restrict__ bcur, int* __restrict__ pairs) {
    __shared__ int cnt[NBUK];
    __shared__ int scanb[NBUK + 1];
    __shared__ int cur[NBUK];
    __shared__ int gbase[NBUK];
    __shared__ int pbuf[P1E];
    __shared__ unsigned char bsl[P1E];
    int t = threadIdx.x;
    int e0 = blockIdx.x * P1E;
    int m = NE - e0; if (m > P1E) m = P1E;
    cnt[t] = 0;
    __syncthreads();
    int ds[16], ss[16], bk[16];
#pragma unroll
    for (int j = 0; j < 16; ++j) {
        int e = t + j * 256;
        if (e < m) {
            ds[j] = dst[e0 + e];
            ss[j] = src[e0 + e];
            bk[j] = ds[j] / BNODES;
            atomicAdd(&cnt[bk[j]], 1);
        } else bk[j] = -1;
    }
    __syncthreads();
    int v = cnt[t];
    scanb[t] = v;
    __syncthreads();
    for (int off = 1; off < 256; off <<= 1) {
        int u = (t >= off) ? scanb[t - off] : 0;
        __syncthreads();
        scanb[t] += u;
        __syncthreads();
    }
    int excl = scanb[t] - v;
    scanb[t] = excl;
    cur[t] = excl;
    if (t == 255) scanb[256] = excl + v;
    __syncthreads();
#pragma unroll
    for (int j = 0; j < 16; ++j) {
        if (bk[j] >= 0) {
            int p = atomicAdd(&cur[bk[j]], 1);
            pbuf[p] = ss[j] | ((ds[j] - bk[j] * BNODES) << 17);
            bsl[p] = (unsigned char)bk[j];
        }
    }
    int cb = scanb[t + 1] - scanb[t];
    if (cb > 0) gbase[t] = atomicAdd(&bcur[t], cb);
    __syncthreads();
    for (int s = t; s < m; s += 256) {
        int b = bsl[s];
        pairs[gbase[b] + (s - scanb[b])] = pbuf[s];
    }
}

__global__ __launch_bounds__(256) void k_pass2(
    const int* __restrict__ pairs, const int* __restrict__ bbase,
    int* __restrict__ deg, int* __restrict__ rs, int* __restrict__ csr) {
    __shared__ int buf1[BUFCAP];
    __shared__ int buf2[BUFCAP];
    __shared__ int cnt[512];
    __shared__ int rsl[512];
    __shared__ int cur[512];
    __shared__ int s1[256];
    int b = blockIdx.x;
    int n0 = b * BNODES;
    if (n0 >= NN) return;
    int nlocal = NN - n0; if (nlocal > BNODES) nlocal = BNODES;
    int t = threadIdx.x;
    int base = bbase[b];
    int m = bbase[b + 1] - base;
    bool fits = (m <= BUFCAP);
    cnt[t] = 0; cnt[t + 256] = 0;
    __syncthreads();
    for (int s = t; s < m; s += 256) {
        int pk = pairs[base + s];
        if (fits) buf1[s] = pk;
        atomicAdd(&cnt[(uint)pk >> 17], 1);
    }
    __syncthreads();
    int c0 = cnt[2 * t], c1 = cnt[2 * t + 1];
    int ps = c0 + c1;
    s1[t] = ps;
    __syncthreads();
    for (int off = 1; off < 256; off <<= 1) {
        int u = (t >= off) ? s1[t - off] : 0;
        __syncthreads();
        s1[t] += u;
        __syncthreads();
    }
    int pexcl = s1[t] - ps;
    rsl[2 * t] = pexcl;          cur[2 * t] = pexcl;
    rsl[2 * t + 1] = pexcl + c0; cur[2 * t + 1] = pexcl + c0;
    __syncthreads();
    for (int i = t; i < nlocal; i += 256) {
        deg[n0 + i] = cnt[i];
        rs[n0 + i] = base + rsl[i];
    }
    if (fits) {
        for (int s = t; s < m; s += 256) {
            int pk = buf1[s];
            int p = atomicAdd(&cur[(uint)pk >> 17], 1);
            buf2[p] = pk & 0x1FFFF;
        }
        __syncthreads();
        for (int s = t; s < m; s += 256) csr[base + s] = buf2[s];
    } else {
        for (int s = t; s < m; s += 256) {
            int pk = pairs[base + s];
            int p = atomicAdd(&cur[(uint)pk >> 17], 1);
            csr[base + p] = pk & 0x1FFFF;
        }
    }
}

// ---------------- x prepack: [N,14] f32 -> [N,16] fp16 (8 uints/row) ----------------

__global__ void k_packx(const float* __restrict__ x, uint* __restrict__ xh) {
    int t = blockIdx.x * blockDim.x + threadIdx.x;
    if (t < NN * 8) {
        int row = t >> 3, q = t & 7;
        int j0 = 2 * q, j1 = 2 * q + 1;
        float f0 = (j0 < FIN) ? x[row * FIN + j0] : 0.f;
        float f1 = (j1 < FIN) ? x[row * FIN + j1] : 0.f;
        xh[t] = pkh(f0, f1);
    }
}

// ---------------- Layer 1: 8-chain predicated single-pass gather ----------------

__global__ __launch_bounds__(256, 6) void k_layer1(
    const float* __restrict__ x, const uint* __restrict__ xh, uint* __restrict__ hout,
    const float* __restrict__ Wl, const float* __restrict__ Wr, const float* __restrict__ b,
    const int* __restrict__ rs, const int* __restrict__ deg, const int* __restrict__ csr) {
    __shared__ float2 sW[FIN][HD];
    __shared__ float sb[HD];
    __shared__ float2 sAH[4][16];
    for (int i = threadIdx.x; i < FIN * HD; i += 256) {
        int k = i >> 6, j = i & 63;
        sW[k][j] = make_float2(Wl[i], Wr[i]);
    }
    if (threadIdx.x < HD) sb[threadIdx.x] = b[threadIdx.x];
    __syncthreads();
    int lane = threadIdx.x & 63, wid = threadIdx.x >> 6;
    int sub = lane >> 3;     // edge slot 0..7
    int fq = lane & 7;       // uint index in row
    int ngroups = (NN + 3) / 4;
    for (int g = blockIdx.x; g < ngroups; g += gridDim.x) {
        int n = g * 4 + wid;
        bool act = n < NN;
        if (act) {
            int s0 = rs[n], d = deg[n];
            float xv = (lane < FIN) ? x[n * FIN + lane] : 0.f;
            __half2 Z = __float2half2_rn(0.f);
            __half2 A[8];
#pragma unroll
            for (int c = 0; c < 8; ++c) A[c] = Z;
            for (int base = 0; base < d; base += 64) {
                int rem = d - base; if (rem > 64) rem = 64;
                int idxv = (lane < rem) ? csr[s0 + base + lane] : 0;
#pragma unroll
                for (int c = 0; c < 8; ++c) {
                    int e = 8 * c + sub;               // <= 63, always-valid shfl index
                    int ii = __shfl(idxv, e);
                    if (e < rem)
                        A[c] = __hadd2(A[c], u2h(xh[(size_t)ii * 8 + fq]));
                }
            }
            A[0] = __hadd2(A[0], A[1]); A[2] = __hadd2(A[2], A[3]);
            A[4] = __hadd2(A[4], A[5]); A[6] = __hadd2(A[6], A[7]);
            A[0] = __hadd2(A[0], A[2]); A[4] = __hadd2(A[4], A[6]);
            A[0] = __hadd2(A[0], A[4]);
            A[0] = hredx(A[0], 8); A[0] = hredx(A[0], 16); A[0] = hredx(A[0], 32);
            float ax = __low2float(A[0]), ay = __high2float(A[0]);
            float inv = 1.0f / (float)(d > 1 ? d : 1);
            float e0 = __shfl(ax, lane >> 1);
            float e1 = __shfl(ay, lane >> 1);
            float sel = (lane & 1) ? e1 : e0;
            if (lane < 16) sAH[wid][lane] = make_float2((lane < FIN) ? sel * inv : 0.f, xv);
        }
        // no barrier: sAH[wid] is per-wave scratch
        float out = sb[lane];
#pragma unroll
        for (int k = 0; k < FIN; ++k) {
            float2 w = sW[k][lane];
            float2 ah = sAH[wid][k];
            out += ah.x * w.x + ah.y * w.y;
        }
        out = fmaxf(out, 0.f);
        float o2 = __shfl_xor(out, 1);
        if (act && !(lane & 1)) hout[(size_t)n * 32 + (lane >> 1)] = pkh(out, o2);
    }
}

// ---------------- H layers: 16-chain predicated single-pass gather + reg-weight MFMA ----------------
// Block = 16 nodes; wave w gathers nodes 4w..4w+3, owns output tile t=w (feats 16w..16w+15).

template <bool FUSEZ>
__global__ __launch_bounds__(256, 4) void k_layerH(
    const uint* __restrict__ hin, uint* __restrict__ hout,
    const float* __restrict__ Wl, const float* __restrict__ Wr, const float* __restrict__ b,
    const float* __restrict__ W4l, const float* __restrict__ W4r, const float* __restrict__ b4g,
    float* __restrict__ z, float* __restrict__ s2,
    const int* __restrict__ rs, const int* __restrict__ deg, const int* __restrict__ csr) {
    __shared__ uint AH[16 * 64];        // bf16 [16 nodes][128 feats], XOR-swizzled: 4 KB
    __shared__ float zb[4][16][4];      // cross-wave z/s partials
    int lane = threadIdx.x & 63, wid = threadIdx.x >> 6;
    int r16 = lane & 15, qg = lane >> 4;
    int jj = 16 * wid + r16;            // output feature this lane owns
    // ---- B-frags from global into registers (L2-hot weights) ----
    short8 bfr[4];
#pragma unroll
    for (int c = 0; c < 4; ++c) {
#pragma unroll
        for (int i = 0; i < 8; ++i) {
            int k = 32 * c + 8 * qg + i;
            float v = (k < 64) ? Wl[k * 64 + jj] : Wr[(k - 64) * 64 + jj];
            bfr[c][i] = bf16of(v);
        }
    }
    float bv = b[jj];
    float wz0 = 0.f, wz1 = 0.f, ws0 = 0.f, ws1 = 0.f;
    if (FUSEZ) {
        wz0 = W4l[jj * NC + 0]; wz1 = W4l[jj * NC + 1];
        ws0 = W4r[jj * NC + 0]; ws1 = W4r[jj * NC + 1];
    }
    // ---- gather phase: 4 nodes per wave, 16-chain predicated single pass ----
    int sub = lane >> 4;       // edge slot 0..3
    int fq = lane & 15;        // uint2 index in row
    const uint2* hb2 = (const uint2*)hin;
    int n0 = blockIdx.x * 16;
    for (int i = 0; i < 4; ++i) {
        int irow = wid * 4 + i;
        int n = n0 + irow;
        int swz = (irow & 7) << 2;
        if (n < NN) {
            int s0 = rs[n], d = deg[n];
            __half2 Zh = __float2half2_rn(0.f);
            __half2 P[16], Q[16];
#pragma unroll
            for (int c = 0; c < 16; ++c) { P[c] = Zh; Q[c] = Zh; }
            for (int base = 0; base < d; base += 64) {
                int rem = d - base; if (rem > 64) rem = 64;
                int idxv = (lane < rem) ? csr[s0 + base + lane] : 0;
#pragma unroll
                for (int c = 0; c < 16; ++c) {
                    int e = 4 * c + sub;               // <= 63, always-valid shfl index
                    int ii = __shfl(idxv, e);
                    if (e < rem) {
                        uint2 U = hb2[(size_t)ii * 16 + fq];
                        P[c] = __hadd2(P[c], u2h(U.x));
                        Q[c] = __hadd2(Q[c], u2h(U.y));
                    }
                }
            }
#pragma unroll
            for (int c = 0; c < 8; ++c) { P[c] = __hadd2(P[c], P[c + 8]); Q[c] = __hadd2(Q[c], Q[c + 8]); }
#pragma unroll
            for (int c = 0; c < 4; ++c) { P[c] = __hadd2(P[c], P[c + 4]); Q[c] = __hadd2(Q[c], Q[c + 4]); }
            P[0] = __hadd2(P[0], P[1]); P[2] = __hadd2(P[2], P[3]);
            Q[0] = __hadd2(Q[0], Q[1]); Q[2] = __hadd2(Q[2], Q[3]);
            P[0] = __hadd2(P[0], P[2]); Q[0] = __hadd2(Q[0], Q[2]);
            P[0] = hredx(P[0], 16); P[0] = hredx(P[0], 32);
            Q[0] = hredx(Q[0], 16); Q[0] = hredx(Q[0], 32);
            float inv = 1.0f / (float)(d > 1 ? d : 1);
            if (lane < 16) {
                float ax = __low2float(P[0]) * inv, ay = __high2float(P[0]) * inv;
                float az = __low2float(Q[0]) * inv, aw = __high2float(Q[0]) * inv;
                uint2* p = (uint2*)&AH[irow * 64 + ((2 * fq) ^ swz)];
                *p = make_uint2(pack2bf16(ax, ay), pack2bf16(az, aw));
            }
            if (lane < 32) {
                __half2 hh = u2h(hin[(size_t)n * 32 + lane]);
                AH[irow * 64 + ((32 + lane) ^ swz)] = pack2bf16(__low2float(hh), __high2float(hh));
            }
        } else {
            AH[irow * 64 + lane] = 0;
        }
    }
    __syncthreads();
    // ---- MFMA dense: OUT[16 nodes][16 feats of tile wid] ----
    f32x4 acc = (f32x4){bv, bv, bv, bv};
#pragma unroll
    for (int c = 0; c < 4; ++c) {
        U128 a;
        a.u = *(const uint4*)&AH[r16 * 64 + ((16 * c + 4 * qg) ^ ((r16 & 7) << 2))];
        acc = __builtin_amdgcn_mfma_f32_16x16x32_bf16(a.s, bfr[c], acc, 0, 0, 0);
    }
    // ---- epilogue: relu, fp16 store, z/s partials ----
    float rz0[4], rz1[4], rs0[4], rs1[4];
#pragma unroll
    for (int r = 0; r < 4; ++r) {
        int m = n0 + qg * 4 + r;           // C/D row = node
        float out = fmaxf(acc[r], 0.f);
        float o2 = __shfl_xor(out, 1);
        if (!(lane & 1) && m < NN)
            hout[(size_t)m * 32 + 8 * wid + (r16 >> 1)] = pkh(out, o2);
        if (FUSEZ) {
            rz0[r] = out * wz0; rz1[r] = out * wz1;
            rs0[r] = out * ws0; rs1[r] = out * ws1;
        }
    }
    if (FUSEZ) {
#pragma unroll
        for (int r = 0; r < 4; ++r) {
            float a0 = rz0[r], a1 = rz1[r], b0 = rs0[r], b1 = rs1[r];
            for (int off = 1; off < 16; off <<= 1) {
                a0 += __shfl_xor(a0, off);
                a1 += __shfl_xor(a1, off);
                b0 += __shfl_xor(b0, off);
                b1 += __shfl_xor(b1, off);
            }
            if (r16 == 0) {
                zb[wid][qg * 4 + r][0] = a0; zb[wid][qg * 4 + r][1] = a1;
                zb[wid][qg * 4 + r][2] = b0; zb[wid][qg * 4 + r][3] = b1;
            }
        }
        __syncthreads();
        int t = threadIdx.x;
        if (t < 16 && n0 + t < NN) {
            float a0 = zb[0][t][0] + zb[1][t][0] + zb[2][t][0] + zb[3][t][0];
            float a1 = zb[0][t][1] + zb[1][t][1] + zb[2][t][1] + zb[3][t][1];
            float c0 = zb[0][t][2] + zb[1][t][2] + zb[2][t][2] + zb[3][t][2];
            float c1 = zb[0][t][3] + zb[1][t][3] + zb[2][t][3] + zb[3][t][3];
            ((float2*)z)[n0 + t] = make_float2(a0, a1);
            ((float2*)s2)[n0 + t] = make_float2(c0 + b4g[0], c1 + b4g[1]);
        }
    }
}

// ---------------- graph pooling: gather z over neighbors + fused self-term ----------------

__global__ __launch_bounds__(256) void k_pool(
    const float* __restrict__ z, const float* __restrict__ s2,
    const int* __restrict__ rs, const int* __restrict__ deg, const int* __restrict__ csr,
    const int* __restrict__ batch, float* __restrict__ gsum) {
    const float2* z2 = (const float2*)z;
    const float2* s22 = (const float2*)s2;
    int lane = threadIdx.x & 63, wid = threadIdx.x >> 6;
    int stride = gridDim.x * 4;
    for (int n = blockIdx.x * 4 + wid; n < NN; n += stride) {
        int s0 = rs[n], d = deg[n];
        float a0 = 0.f, a1 = 0.f;
        for (int j = lane; j < d; j += 64) {
            int s = csr[s0 + j];
            float2 zv = z2[s];
            a0 += zv.x;
            a1 += zv.y;
        }
        for (int off = 32; off; off >>= 1) {
            a0 += __shfl_xor(a0, off);
            a1 += __shfl_xor(a1, off);
        }
        if (lane == 0) {
            float2 sv = s22[n];
            float inv = 1.0f / (float)(d > 1 ? d : 1);
            float o0 = a0 * inv + sv.x;
            float o1 = a1 * inv + sv.y;
            int gg = batch[n];
            atomicAdd(&gsum[gg * 2 + 0], o0);
            atomicAdd(&gsum[gg * 2 + 1], o1);
        }
    }
}

__global__ void k_final(const float* __restrict__ gsum, const int* __restrict__ gstart,
                        const int* __restrict__ gend, float* __restrict__ out) {
    int g = blockIdx.x * blockDim.x + threadIdx.x;
    if (g < NG) {
        int cnt = gend[g] - gstart[g];
        float inv = 1.0f / (float)(cnt > 1 ? cnt : 1);
        float p0 = gsum[g * 2 + 0] * inv;
        float p1 = gsum[g * 2 + 1] * inv;
        float m = fmaxf(p0, p1);
        float lse = m + logf(expf(p0 - m) + expf(p1 - m));
        out[g * 2 + 0] = p0 - lse;
        out[g * 2 + 1] = p1 - lse;
    }
}

// ---------------- launch ----------------

extern "C" void kernel_launch(void* const* d_in, const int* in_sizes, int n_in,
                              void* d_out, int out_size, void* d_ws, size_t ws_size,
                              hipStream_t stream) {
    const float* x   = (const float*)d_in[0];
    const float* W1l = (const float*)d_in[1];
    const float* W1r = (const float*)d_in[2];
    const float* b1  = (const float*)d_in[3];
    const float* W2l = (const float*)d_in[4];
    const float* W2r = (const float*)d_in[5];
    const float* b2  = (const float*)d_in[6];
    const float* W3l = (const float*)d_in[7];
    const float* W3r = (const float*)d_in[8];
    const float* b3  = (const float*)d_in[9];
    const float* W4l = (const float*)d_in[10];
    const float* W4r = (const float*)d_in[11];
    const float* b4  = (const float*)d_in[12];
    const int* ei    = (const int*)d_in[13];
    const int* batch = (const int*)d_in[14];
    const int* src = ei;
    const int* dst = ei + NE;
    float* out = (float*)d_out;

    char* w = (char*)d_ws;
    int* deg    = (int*)w; w += (size_t)NN * 4;
    int* rs     = (int*)w; w += (size_t)NN * 4;
    int* csr    = (int*)w; w += (size_t)NE * 4;
    int* gstart = (int*)w; w += (size_t)NG * 4;
    int* gend   = (int*)w; w += (size_t)NG * 4;
    int* bkcnt  = (int*)w; w += NBUK * 4;
    int* bbase  = (int*)w; w += (NBUK + 1) * 4;
    int* bcur   = (int*)w; w += NBUK * 4;
    w = (char*)(((uintptr_t)w + 255) & ~(uintptr_t)255);
    uint* xh    = (uint*)w; w += (size_t)NN * 8 * 4;
    uint* hA    = (uint*)w; w += (size_t)NN * 32 * 4;
    uint* hB    = (uint*)w; w += (size_t)NN * 32 * 4;
    float* z    = (float*)w; w += (size_t)NN * NC * 4;
    float* s2   = (float*)w; w += (size_t)NN * NC * 4;
    float* gsum = (float*)w; w += (size_t)NG * NC * 4;
    int* pairs = (int*)hB;  // alias: NE*4 == NN*32*4 bytes; dead before layer 2 writes hB

    const int P1B = (NE + P1E - 1) / P1E;  // 782
    const int HGB = (NN + 15) / 16;        // 6250 layerH blocks

    hipMemsetAsync(bkcnt, 0, NBUK * 4, stream);
    hipMemsetAsync(gstart, 0, (size_t)NG * 4, stream);
    hipMemsetAsync(gend, 0, (size_t)NG * 4, stream);
    hipMemsetAsync(gsum, 0, (size_t)NG * NC * 4, stream);

    k_hist_bucket<<<P1B, 256, 0, stream>>>(dst, bkcnt);
    k_packx<<<(NN * 8 + 255) / 256, 256, 0, stream>>>(x, xh);
    k_gbounds<<<(NN + 255) / 256, 256, 0, stream>>>(batch, gstart, gend);
    k_scanb<<<1, NBUK, 0, stream>>>(bkcnt, bbase, bcur);
    k_pass1<<<P1B, 256, 0, stream>>>(src, dst, bcur, pairs);
    k_pass2<<<NBUK, 256, 0, stream>>>(pairs, bbase, deg, rs, csr);

    k_layer1<<<1536, 256, 0, stream>>>(x, xh, hA, W1l, W1r, b1, rs, deg, csr);
    k_layerH<false><<<HGB, 256, 0, stream>>>(hA, hB, W2l, W2r, b2,
                                             nullptr, nullptr, nullptr, nullptr, nullptr,
                                             rs, deg, csr);
    k_layerH<true><<<HGB, 256, 0, stream>>>(hB, hA, W3l, W3r, b3,
                                            W4l, W4r, b4, z, s2,
                                            rs, deg, csr);
    k_pool<<<2048, 256, 0, stream>>>(z, s2, rs, deg, csr, batch, gsum);
    k_final<<<(NG + 255) / 256, 256, 0, stream>>>(gsum, gstart, gend, out);
}

// Round 18
// 422.589 us; speedup vs baseline: 1.2026x; 1.2026x over previous
//
#include <hip/hip_runtime.h>
#include <hip/hip_fp16.h>

#define NN 100000
#define NE 3200000
#define NG 2000
#define FIN 14
#define HD 64
#define NC 2

#define NBUK 256
#define BNODES 391      // 256*391 = 100096 >= NN
#define P1E 4096        // edges per pass-1 block
#define BUFCAP 13312    // pass-2 LDS csr slice capacity (mean 12500, +7 sigma)

typedef unsigned int uint;
typedef short short8 __attribute__((ext_vector_type(8)));
typedef float f32x4 __attribute__((ext_vector_type(4)));
union U128 { uint4 u; short8 s; };

__device__ __forceinline__ __half2 u2h(uint u) {
    union { uint u; __half2 h; } c; c.u = u; return c.h;
}
__device__ __forceinline__ uint h2u(__half2 h) {
    union { __half2 h; uint u; } c; c.h = h; return c.u;
}
__device__ __forceinline__ uint pkh(float a, float b) {
    return h2u(__floats2half2_rn(a, b));
}
__device__ __forceinline__ uint pack2bf16(float a, float b) {
    uint ua = __float_as_uint(a), ub = __float_as_uint(b);
    ua = (ua + 0x7FFFu + ((ua >> 16) & 1u)) >> 16;
    ub = (ub + 0x7FFFu + ((ub >> 16) & 1u)) >> 16;
    return ua | (ub << 16);
}
__device__ __forceinline__ short bf16of(float a) {
    uint ua = __float_as_uint(a);
    return (short)((ua + 0x7FFFu + ((ua >> 16) & 1u)) >> 16);
}
// packed-fp16 xor-reduce step
__device__ __forceinline__ __half2 hredx(__half2 v, int off) {
    return __hadd2(v, u2h((uint)__shfl_xor((int)h2u(v), off)));
}

// ---------------- bucket histogram (LDS-privatized) ----------------

__global__ __launch_bounds__(256) void k_hist_bucket(const int* __restrict__ dst,
                                                     int* __restrict__ bkcnt) {
    __shared__ int cnt[NBUK];
    int t = threadIdx.x;
    cnt[t] = 0;
    __syncthreads();
    int e0 = blockIdx.x * P1E;
    int m = NE - e0; if (m > P1E) m = P1E;
    for (int e = t; e < m; e += 256) atomicAdd(&cnt[dst[e0 + e] / BNODES], 1);
    __syncthreads();
    if (cnt[t] > 0) atomicAdd(&bkcnt[t], cnt[t]);
}

__global__ void k_scanb(const int* __restrict__ bkcnt, int* __restrict__ bbase,
                        int* __restrict__ bcur) {
    __shared__ int tmp[NBUK];
    int t = threadIdx.x;
    int v = bkcnt[t];
    tmp[t] = v;
    __syncthreads();
    for (int off = 1; off < NBUK; off <<= 1) {
        int u = (t >= off) ? tmp[t - off] : 0;
        __syncthreads();
        tmp[t] += u;
        __syncthreads();
    }
    int excl = tmp[t] - v;
    bbase[t] = excl;
    bcur[t] = excl;
    if (t == NBUK - 1) bbase[NBUK] = tmp[t];
}

__global__ void k_gbounds(const int* __restrict__ batch, int* __restrict__ gstart,
                          int* __restrict__ gend) {
    int i = blockIdx.x * blockDim.x + threadIdx.x;
    if (i < NN) {
        int b = batch[i];
        if (i == 0 || batch[i - 1] != b) gstart[b] = i;
        if (i == NN - 1 || batch[i + 1] != b) gend[b] = i + 1;
    }
}

__global__ __launch_bounds__(256) void k_pass1(
    const int* __restrict__ src, const int* __restrict__ dst,
    int* __restrict__ bcur, int* __restrict__ pairs) {
    __shared__ int cnt[NBUK];
    __shared__ int scanb[NBUK + 1];
    __shared__ int cur[NBUK];
    __shared__ int gbase[NBUK];
    __shared__ int pbuf[P1E];
    __shared__ unsigned char bsl[P1E];
    int t = threadIdx.x;
    int e0 = blockIdx.x * P1E;
    int m = NE - e0; if (m > P1E) m = P1E;
    cnt[t] = 0;
    __syncthreads();
    int ds[16], ss[16], bk[16];
#pragma unroll
    for (int j = 0; j < 16; ++j) {
        int e = t + j * 256;
        if (e < m) {
            ds[j] = dst[e0 + e];
            ss[j] = src[e0 + e];
            bk[j] = ds[j] / BNODES;
            atomicAdd(&cnt[bk[j]], 1);
        } else bk[j] = -1;
    }
    __syncthreads();
    int v = cnt[t];
    scanb[t] = v;
    __syncthreads();
    for (int off = 1; off < 256; off <<= 1) {
        int u = (t >= off) ? scanb[t - off] : 0;
        __syncthreads();
        scanb[t] += u;
        __syncthreads();
    }
    int excl = scanb[t] - v;
    scanb[t] = excl;
    cur[t] = excl;
    if (t == 255) scanb[256] = excl + v;
    __syncthreads();
#pragma unroll
    for (int j = 0; j < 16; ++j) {
        if (bk[j] >= 0) {
            int p = atomicAdd(&cur[bk[j]], 1);
            pbuf[p] = ss[j] | ((ds[j] - bk[j] * BNODES) << 17);
            bsl[p] = (unsigned char)bk[j];
        }
    }
    int cb = scanb[t + 1] - scanb[t];
    if (cb > 0) gbase[t] = atomicAdd(&bcur[t], cb);
    __syncthreads();
    for (int s = t; s < m; s += 256) {
        int b = bsl[s];
        pairs[gbase[b] + (s - scanb[b])] = pbuf[s];
    }
}

__global__ __launch_bounds__(256) void k_pass2(
    const int* __restrict__ pairs, const int* __restrict__ bbase,
    int* __restrict__ deg, int* __restrict__ rs, int* __restrict__ csr) {
    __shared__ int buf1[BUFCAP];
    __shared__ int buf2[BUFCAP];
    __shared__ int cnt[512];
    __shared__ int rsl[512];
    __shared__ int cur[512];
    __shared__ int s1[256];
    int b = blockIdx.x;
    int n0 = b * BNODES;
    if (n0 >= NN) return;
    int nlocal = NN - n0; if (nlocal > BNODES) nlocal = BNODES;
    int t = threadIdx.x;
    int base = bbase[b];
    int m = bbase[b + 1] - base;
    bool fits = (m <= BUFCAP);
    cnt[t] = 0; cnt[t + 256] = 0;
    __syncthreads();
    for (int s = t; s < m; s += 256) {
        int pk = pairs[base + s];
        if (fits) buf1[s] = pk;
        atomicAdd(&cnt[(uint)pk >> 17], 1);
    }
    __syncthreads();
    int c0 = cnt[2 * t], c1 = cnt[2 * t + 1];
    int ps = c0 + c1;
    s1[t] = ps;
    __syncthreads();
    for (int off = 1; off < 256; off <<= 1) {
        int u = (t >= off) ? s1[t - off] : 0;
        __syncthreads();
        s1[t] += u;
        __syncthreads();
    }
    int pexcl = s1[t] - ps;
    rsl[2 * t] = pexcl;          cur[2 * t] = pexcl;
    rsl[2 * t + 1] = pexcl + c0; cur[2 * t + 1] = pexcl + c0;
    __syncthreads();
    for (int i = t; i < nlocal; i += 256) {
        deg[n0 + i] = cnt[i];
        rs[n0 + i] = base + rsl[i];
    }
    if (fits) {
        for (int s = t; s < m; s += 256) {
            int pk = buf1[s];
            int p = atomicAdd(&cur[(uint)pk >> 17], 1);
            buf2[p] = pk & 0x1FFFF;
        }
        __syncthreads();
        for (int s = t; s < m; s += 256) csr[base + s] = buf2[s];
    } else {
        for (int s = t; s < m; s += 256) {
            int pk = pairs[base + s];
            int p = atomicAdd(&cur[(uint)pk >> 17], 1);
            csr[base + p] = pk & 0x1FFFF;
        }
    }
}

// ---------------- x prepack: [N,14] f32 -> [N,16] fp16 (8 uints/row) ----------------

__global__ void k_packx(const float* __restrict__ x, uint* __restrict__ xh) {
    int t = blockIdx.x * blockDim.x + threadIdx.x;
    if (t < NN * 8) {
        int row = t >> 3, q = t & 7;
        int j0 = 2 * q, j1 = 2 * q + 1;
        float f0 = (j0 < FIN) ? x[row * FIN + j0] : 0.f;
        float f1 = (j1 < FIN) ? x[row * FIN + j1] : 0.f;
        xh[t] = pkh(f0, f1);
    }
}

// ---------------- Layer 1: fp16 rows, shfl-broadcast gather, packed-half accumulate ----------------

__global__ __launch_bounds__(256, 6) void k_layer1(
    const float* __restrict__ x, const uint* __restrict__ xh, uint* __restrict__ hout,
    const float* __restrict__ Wl, const float* __restrict__ Wr, const float* __restrict__ b,
    const int* __restrict__ rs, const int* __restrict__ deg, const int* __restrict__ csr) {
    __shared__ float2 sW[FIN][HD];
    __shared__ float sb[HD];
    __shared__ float2 sAH[4][16];
    for (int i = threadIdx.x; i < FIN * HD; i += 256) {
        int k = i >> 6, j = i & 63;
        sW[k][j] = make_float2(Wl[i], Wr[i]);
    }
    if (threadIdx.x < HD) sb[threadIdx.x] = b[threadIdx.x];
    __syncthreads();
    int lane = threadIdx.x & 63, wid = threadIdx.x >> 6;
    int sub = lane >> 3;
    int fq = lane & 7;
    int ngroups = (NN + 3) / 4;
    for (int g = blockIdx.x; g < ngroups; g += gridDim.x) {
        int n = g * 4 + wid;
        bool act = n < NN;
        if (act) {
            int s0 = rs[n], d = deg[n];
            float xv = (lane < FIN) ? x[n * FIN + lane] : 0.f;
            __half2 Z = __float2half2_rn(0.f);
            __half2 A0 = Z, A1 = Z, A2 = Z, A3 = Z, A4 = Z, A5 = Z, A6 = Z, A7 = Z;
            for (int base = 0; base < d; base += 64) {
                int rem = d - base; if (rem > 64) rem = 64;
                int idxv = (lane < rem) ? csr[s0 + base + lane] : 0;
                int j = 0;
                for (; j + 64 <= rem; j += 64) {
                    int i0 = __shfl(idxv, j + 0 + sub);
                    int i1 = __shfl(idxv, j + 8 + sub);
                    int i2 = __shfl(idxv, j + 16 + sub);
                    int i3 = __shfl(idxv, j + 24 + sub);
                    int i4 = __shfl(idxv, j + 32 + sub);
                    int i5 = __shfl(idxv, j + 40 + sub);
                    int i6 = __shfl(idxv, j + 48 + sub);
                    int i7 = __shfl(idxv, j + 56 + sub);
                    A0 = __hadd2(A0, u2h(xh[(size_t)i0 * 8 + fq]));
                    A1 = __hadd2(A1, u2h(xh[(size_t)i1 * 8 + fq]));
                    A2 = __hadd2(A2, u2h(xh[(size_t)i2 * 8 + fq]));
                    A3 = __hadd2(A3, u2h(xh[(size_t)i3 * 8 + fq]));
                    A4 = __hadd2(A4, u2h(xh[(size_t)i4 * 8 + fq]));
                    A5 = __hadd2(A5, u2h(xh[(size_t)i5 * 8 + fq]));
                    A6 = __hadd2(A6, u2h(xh[(size_t)i6 * 8 + fq]));
                    A7 = __hadd2(A7, u2h(xh[(size_t)i7 * 8 + fq]));
                }
                for (; j + 8 <= rem; j += 8) {
                    int i0 = __shfl(idxv, j + sub);
                    A0 = __hadd2(A0, u2h(xh[(size_t)i0 * 8 + fq]));
                }
                if (j < rem) {
                    int i0 = __shfl(idxv, j + sub);
                    if (sub < rem - j) A0 = __hadd2(A0, u2h(xh[(size_t)i0 * 8 + fq]));
                }
            }
            A0 = __hadd2(A0, A1); A2 = __hadd2(A2, A3);
            A4 = __hadd2(A4, A5); A6 = __hadd2(A6, A7);
            A0 = __hadd2(A0, A2); A4 = __hadd2(A4, A6);
            A0 = __hadd2(A0, A4);
            A0 = hredx(A0, 8); A0 = hredx(A0, 16); A0 = hredx(A0, 32);
            float ax = __low2float(A0), ay = __high2float(A0);
            float inv = 1.0f / (float)(d > 1 ? d : 1);
            float e0 = __shfl(ax, lane >> 1);
            float e1 = __shfl(ay, lane >> 1);
            float sel = (lane & 1) ? e1 : e0;
            if (lane < 16) sAH[wid][lane] = make_float2((lane < FIN) ? sel * inv : 0.f, xv);
        }
        // no barrier: sAH[wid] is per-wave scratch
        float out = sb[lane];
#pragma unroll
        for (int k = 0; k < FIN; ++k) {
            float2 w = sW[k][lane];
            float2 ah = sAH[wid][k];
            out += ah.x * w.x + ah.y * w.y;
        }
        out = fmaxf(out, 0.f);
        float o2 = __shfl_xor(out, 1);
        if (act && !(lane & 1)) hout[(size_t)n * 32 + (lane >> 1)] = pkh(out, o2);
    }
}

// ---------------- H layers: R11 gather + register-weight MFMA + fused pool epilogue ----------------
// Block = 16 nodes; wave w gathers nodes 4w..4w+3, owns output tile t=w (feats 16w..16w+15).

template <bool FUSEZ>
__global__ __launch_bounds__(256, 4) void k_layerH(
    const uint* __restrict__ hin, uint* __restrict__ hout,
    const float* __restrict__ Wl, const float* __restrict__ Wr, const float* __restrict__ b,
    const float* __restrict__ W4l, const float* __restrict__ W4r, const float* __restrict__ b4g,
    float* __restrict__ z, float* __restrict__ s2,
    const int* __restrict__ rs, const int* __restrict__ deg, const int* __restrict__ csr) {
    __shared__ uint AH[16 * 64];        // bf16 [16 nodes][128 feats], XOR-swizzled: 4 KB
    __shared__ float zb[4][16][4];      // cross-wave z/s partials
    int lane = threadIdx.x & 63, wid = threadIdx.x >> 6;
    int r16 = lane & 15, qg = lane >> 4;
    int jj = 16 * wid + r16;            // output feature this lane owns
    // ---- B-frags from global into registers (L2-hot weights) ----
    short8 bfr[4];
#pragma unroll
    for (int c = 0; c < 4; ++c) {
#pragma unroll
        for (int i = 0; i < 8; ++i) {
            int k = 32 * c + 8 * qg + i;
            float v = (k < 64) ? Wl[k * 64 + jj] : Wr[(k - 64) * 64 + jj];
            bfr[c][i] = bf16of(v);
        }
    }
    float bv = b[jj];
    float wz0 = 0.f, wz1 = 0.f, ws0 = 0.f, ws1 = 0.f;
    if (FUSEZ) {
        wz0 = W4l[jj * NC + 0]; wz1 = W4l[jj * NC + 1];
        ws0 = W4r[jj * NC + 0]; ws1 = W4r[jj * NC + 1];
    }
    // ---- gather phase: 4 nodes per wave, shfl-broadcast indices, spill bf16 rows ----
    int sub = lane >> 4;       // edge slot 0..3
    int fq = lane & 15;        // uint2 index in row
    const uint2* hb2 = (const uint2*)hin;
    int n0 = blockIdx.x * 16;
    for (int i = 0; i < 4; ++i) {
        int irow = wid * 4 + i;
        int n = n0 + irow;
        int swz = (irow & 7) << 2;
        if (n < NN) {
            int s0 = rs[n], d = deg[n];
            __half2 Zh = __float2half2_rn(0.f);
            __half2 P0 = Zh, P1 = Zh, P2 = Zh, P3 = Zh, P4 = Zh, P5 = Zh, P6 = Zh, P7 = Zh;
            __half2 Q0 = Zh, Q1 = Zh, Q2 = Zh, Q3 = Zh, Q4 = Zh, Q5 = Zh, Q6 = Zh, Q7 = Zh;
            for (int base = 0; base < d; base += 64) {
                int rem = d - base; if (rem > 64) rem = 64;
                int idxv = (lane < rem) ? csr[s0 + base + lane] : 0;
                int j = 0;
                for (; j + 32 <= rem; j += 32) {
                    int i0 = __shfl(idxv, j + 0 + sub);
                    int i1 = __shfl(idxv, j + 4 + sub);
                    int i2 = __shfl(idxv, j + 8 + sub);
                    int i3 = __shfl(idxv, j + 12 + sub);
                    int i4 = __shfl(idxv, j + 16 + sub);
                    int i5 = __shfl(idxv, j + 20 + sub);
                    int i6 = __shfl(idxv, j + 24 + sub);
                    int i7 = __shfl(idxv, j + 28 + sub);
                    uint2 U;
                    U = hb2[(size_t)i0 * 16 + fq]; P0 = __hadd2(P0, u2h(U.x)); Q0 = __hadd2(Q0, u2h(U.y));
                    U = hb2[(size_t)i1 * 16 + fq]; P1 = __hadd2(P1, u2h(U.x)); Q1 = __hadd2(Q1, u2h(U.y));
                    U = hb2[(size_t)i2 * 16 + fq]; P2 = __hadd2(P2, u2h(U.x)); Q2 = __hadd2(Q2, u2h(U.y));
                    U = hb2[(size_t)i3 * 16 + fq]; P3 = __hadd2(P3, u2h(U.x)); Q3 = __hadd2(Q3, u2h(U.y));
                    U = hb2[(size_t)i4 * 16 + fq]; P4 = __hadd2(P4, u2h(U.x)); Q4 = __hadd2(Q4, u2h(U.y));
                    U = hb2[(size_t)i5 * 16 + fq]; P5 = __hadd2(P5, u2h(U.x)); Q5 = __hadd2(Q5, u2h(U.y));
                    U = hb2[(size_t)i6 * 16 + fq]; P6 = __hadd2(P6, u2h(U.x)); Q6 = __hadd2(Q6, u2h(U.y));
                    U = hb2[(size_t)i7 * 16 + fq]; P7 = __hadd2(P7, u2h(U.x)); Q7 = __hadd2(Q7, u2h(U.y));
                }
                for (; j + 4 <= rem; j += 4) {
                    int i0 = __shfl(idxv, j + sub);
                    uint2 U = hb2[(size_t)i0 * 16 + fq];
                    P0 = __hadd2(P0, u2h(U.x)); Q0 = __hadd2(Q0, u2h(U.y));
                }
                if (j < rem) {
                    int i0 = __shfl(idxv, j + sub);
                    if (sub < rem - j) {
                        uint2 U = hb2[(size_t)i0 * 16 + fq];
                        P0 = __hadd2(P0, u2h(U.x)); Q0 = __hadd2(Q0, u2h(U.y));
                    }
                }
            }
            P0 = __hadd2(P0, P1); P2 = __hadd2(P2, P3);
            P4 = __hadd2(P4, P5); P6 = __hadd2(P6, P7);
            Q0 = __hadd2(Q0, Q1); Q2 = __hadd2(Q2, Q3);
            Q4 = __hadd2(Q4, Q5); Q6 = __hadd2(Q6, Q7);
            P0 = __hadd2(P0, P2); P4 = __hadd2(P4, P6);
            Q0 = __hadd2(Q0, Q2); Q4 = __hadd2(Q4, Q6);
            P0 = __hadd2(P0, P4); Q0 = __hadd2(Q0, Q4);
            P0 = hredx(P0, 16); P0 = hredx(P0, 32);
            Q0 = hredx(Q0, 16); Q0 = hredx(Q0, 32);
            float inv = 1.0f / (float)(d > 1 ? d : 1);
            if (lane < 16) {
                float ax = __low2float(P0) * inv, ay = __high2float(P0) * inv;
                float az = __low2float(Q0) * inv, aw = __high2float(Q0) * inv;
                uint2* p = (uint2*)&AH[irow * 64 + ((2 * fq) ^ swz)];
                *p = make_uint2(pack2bf16(ax, ay), pack2bf16(az, aw));
            }
            if (lane < 32) {
                __half2 hh = u2h(hin[(size_t)n * 32 + lane]);
                AH[irow * 64 + ((32 + lane) ^ swz)] = pack2bf16(__low2float(hh), __high2float(hh));
            }
        } else {
            AH[irow * 64 + lane] = 0;
        }
    }
    __syncthreads();
    // ---- MFMA dense: OUT[16 nodes][16 feats of tile wid] ----
    f32x4 acc = (f32x4){bv, bv, bv, bv};
#pragma unroll
    for (int c = 0; c < 4; ++c) {
        U128 a;
        a.u = *(const uint4*)&AH[r16 * 64 + ((16 * c + 4 * qg) ^ ((r16 & 7) << 2))];
        acc = __builtin_amdgcn_mfma_f32_16x16x32_bf16(a.s, bfr[c], acc, 0, 0, 0);
    }
    // ---- epilogue: relu, fp16 store, z/s partials ----
    float rz0[4], rz1[4], rs0[4], rs1[4];
#pragma unroll
    for (int r = 0; r < 4; ++r) {
        int m = n0 + qg * 4 + r;           // C/D row = node
        float out = fmaxf(acc[r], 0.f);
        float o2 = __shfl_xor(out, 1);
        if (!(lane & 1) && m < NN)
            hout[(size_t)m * 32 + 8 * wid + (r16 >> 1)] = pkh(out, o2);
        if (FUSEZ) {
            rz0[r] = out * wz0; rz1[r] = out * wz1;
            rs0[r] = out * ws0; rs1[r] = out * ws1;
        }
    }
    if (FUSEZ) {
#pragma unroll
        for (int r = 0; r < 4; ++r) {
            float a0 = rz0[r], a1 = rz1[r], b0 = rs0[r], b1 = rs1[r];
            for (int off = 1; off < 16; off <<= 1) {
                a0 += __shfl_xor(a0, off);
                a1 += __shfl_xor(a1, off);
                b0 += __shfl_xor(b0, off);
                b1 += __shfl_xor(b1, off);
            }
            if (r16 == 0) {
                zb[wid][qg * 4 + r][0] = a0; zb[wid][qg * 4 + r][1] = a1;
                zb[wid][qg * 4 + r][2] = b0; zb[wid][qg * 4 + r][3] = b1;
            }
        }
        __syncthreads();
        int t = threadIdx.x;
        if (t < 16 && n0 + t < NN) {
            float a0 = zb[0][t][0] + zb[1][t][0] + zb[2][t][0] + zb[3][t][0];
            float a1 = zb[0][t][1] + zb[1][t][1] + zb[2][t][1] + zb[3][t][1];
            float c0 = zb[0][t][2] + zb[1][t][2] + zb[2][t][2] + zb[3][t][2];
            float c1 = zb[0][t][3] + zb[1][t][3] + zb[2][t][3] + zb[3][t][3];
            ((float2*)z)[n0 + t] = make_float2(a0, a1);
            ((float2*)s2)[n0 + t] = make_float2(c0 + b4g[0], c1 + b4g[1]);
        }
    }
}

// ---------------- graph pooling: gather z over neighbors + fused self-term ----------------

__global__ __launch_bounds__(256) void k_pool(
    const float* __restrict__ z, const float* __restrict__ s2,
    const int* __restrict__ rs, const int* __restrict__ deg, const int* __restrict__ csr,
    const int* __restrict__ batch, float* __restrict__ gsum) {
    const float2* z2 = (const float2*)z;
    const float2* s22 = (const float2*)s2;
    int lane = threadIdx.x & 63, wid = threadIdx.x >> 6;
    int stride = gridDim.x * 4;
    for (int n = blockIdx.x * 4 + wid; n < NN; n += stride) {
        int s0 = rs[n], d = deg[n];
        float a0 = 0.f, a1 = 0.f;
        for (int j = lane; j < d; j += 64) {
            int s = csr[s0 + j];
            float2 zv = z2[s];
            a0 += zv.x;
            a1 += zv.y;
        }
        for (int off = 32; off; off >>= 1) {
            a0 += __shfl_xor(a0, off);
            a1 += __shfl_xor(a1, off);
        }
        if (lane == 0) {
            float2 sv = s22[n];
            float inv = 1.0f / (float)(d > 1 ? d : 1);
            float o0 = a0 * inv + sv.x;
            float o1 = a1 * inv + sv.y;
            int gg = batch[n];
            atomicAdd(&gsum[gg * 2 + 0], o0);
            atomicAdd(&gsum[gg * 2 + 1], o1);
        }
    }
}

__global__ void k_final(const float* __restrict__ gsum, const int* __restrict__ gstart,
                        const int* __restrict__ gend, float* __restrict__ out) {
    int g = blockIdx.x * blockDim.x + threadIdx.x;
    if (g < NG) {
        int cnt = gend[g] - gstart[g];
        float inv = 1.0f / (float)(cnt > 1 ? cnt : 1);
        float p0 = gsum[g * 2 + 0] * inv;
        float p1 = gsum[g * 2 + 1] * inv;
        float m = fmaxf(p0, p1);
        float lse = m + logf(expf(p0 - m) + expf(p1 - m));
        out[g * 2 + 0] = p0 - lse;
        out[g * 2 + 1] = p1 - lse;
    }
}

// ---------------- launch ----------------

extern "C" void kernel_launch(void* const* d_in, const int* in_sizes, int n_in,
                              void* d_out, int out_size, void* d_ws, size_t ws_size,
                              hipStream_t stream) {
    const float* x   = (const float*)d_in[0];
    const float* W1l = (const float*)d_in[1];
    const float* W1r = (const float*)d_in[2];
    const float* b1  = (const float*)d_in[3];
    const float* W2l = (const float*)d_in[4];
    const float* W2r = (const float*)d_in[5];
    const float* b2  = (const float*)d_in[6];
    const float* W3l = (const float*)d_in[7];
    const float* W3r = (const float*)d_in[8];
    const float* b3  = (const float*)d_in[9];
    const float* W4l = (const float*)d_in[10];
    const float* W4r = (const float*)d_in[11];
    const float* b4  = (const float*)d_in[12];
    const int* ei    = (const int*)d_in[13];
    const int* batch = (const int*)d_in[14];
    const int* src = ei;
    const int* dst = ei + NE;
    float* out = (float*)d_out;

    char* w = (char*)d_ws;
    int* deg    = (int*)w; w += (size_t)NN * 4;
    int* rs     = (int*)w; w += (size_t)NN * 4;
    int* csr    = (int*)w; w += (size_t)NE * 4;
    int* gstart = (int*)w; w += (size_t)NG * 4;
    int* gend   = (int*)w; w += (size_t)NG * 4;
    int* bkcnt  = (int*)w; w += NBUK * 4;
    int* bbase  = (int*)w; w += (NBUK + 1) * 4;
    int* bcur   = (int*)w; w += NBUK * 4;
    w = (char*)(((uintptr_t)w + 255) & ~(uintptr_t)255);
    uint* xh    = (uint*)w; w += (size_t)NN * 8 * 4;
    uint* hA    = (uint*)w; w += (size_t)NN * 32 * 4;
    uint* hB    = (uint*)w; w += (size_t)NN * 32 * 4;
    float* z    = (float*)w; w += (size_t)NN * NC * 4;
    float* s2   = (float*)w; w += (size_t)NN * NC * 4;
    float* gsum = (float*)w; w += (size_t)NG * NC * 4;
    int* pairs = (int*)hB;  // alias: NE*4 == NN*32*4 bytes; dead before layer 2 writes hB

    const int P1B = (NE + P1E - 1) / P1E;  // 782
    const int HGB = (NN + 15) / 16;        // 6250 layerH blocks

    hipMemsetAsync(bkcnt, 0, NBUK * 4, stream);
    hipMemsetAsync(gstart, 0, (size_t)NG * 4, stream);
    hipMemsetAsync(gend, 0, (size_t)NG * 4, stream);
    hipMemsetAsync(gsum, 0, (size_t)NG * NC * 4, stream);

    k_hist_bucket<<<P1B, 256, 0, stream>>>(dst, bkcnt);
    k_packx<<<(NN * 8 + 255) / 256, 256, 0, stream>>>(x, xh);
    k_gbounds<<<(NN + 255) / 256, 256, 0, stream>>>(batch, gstart, gend);
    k_scanb<<<1, NBUK, 0, stream>>>(bkcnt, bbase, bcur);
    k_pass1<<<P1B, 256, 0, stream>>>(src, dst, bcur, pairs);
    k_pass2<<<NBUK, 256, 0, stream>>>(pairs, bbase, deg, rs, csr);

    k_layer1<<<1536, 256, 0, stream>>>(x, xh, hA, W1l, W1r, b1, rs, deg, csr);
    k_layerH<false><<<HGB, 256, 0, stream>>>(hA, hB, W2l, W2r, b2,
                                             nullptr, nullptr, nullptr, nullptr, nullptr,
                                             rs, deg, csr);
    k_layerH<true><<<HGB, 256, 0, stream>>>(hB, hA, W3l, W3r, b3,
                                            W4l, W4r, b4, z, s2,
                                            rs, deg, csr);
    k_pool<<<2048, 256, 0, stream>>>(z, s2, rs, deg, csr, batch, gsum);
    k_final<<<(NG + 255) / 256, 256, 0, stream>>>(gsum, gstart, gend, out);
}